// Round 5
// baseline (632449.512 us; speedup 1.0000x reference)
//
#include <hip/hip_runtime.h>
#include <math.h>

// ControlledNODE: sequential RK4 scan, T=65536, 1 block / 128 threads (2 waves).
// R4: bit-exact to R0 (validated in R3), minimal instruction count:
//  - L1 x-broadcast via v_readlane (32 values; removes xbuf write+barrier)
//  - L2/L3 broadcast via LDS ds_read_b128 (4 values/instr; R3's readlanes were 4x sparser)
//  - L3 K-split across lane halves + one shfl_xor(32); R0's segment association kept
//  - heads batched 16 steps deep in registers; 4x32-lane groups compute d/t/c
//    with interleaved xor-trees (latency amortized), ~8 instr/step
//  - 2 barriers/stage (z1, z2) = 8/step
// Numerics contract (R1/R2 lesson): every output scalar's fma-chain order must
// match R0 exactly; re-association re-rolls the 65536-step trajectory dice.

constexpr int T_STEPS = 65536;

__device__ __forceinline__ float rl_f(float v, int i) {
    return __uint_as_float(__builtin_amdgcn_readlane(__float_as_uint(v), i));
}
__device__ __forceinline__ float silu_f(float a) {
    return a / (1.0f + __expf(-a));   // EXACT R0 form, IEEE divide
}

__global__ __launch_bounds__(128, 1)
void node_scan(const float* __restrict__ U,
               const float* __restrict__ h0,
               const float* __restrict__ W1, const float* __restrict__ b1,
               const float* __restrict__ W2, const float* __restrict__ b2,
               const float* __restrict__ W3, const float* __restrict__ b3,
               const float* __restrict__ Wd, const float* __restrict__ bd,
               const float* __restrict__ Wt, const float* __restrict__ bt,
               const float* __restrict__ Wc, const float* __restrict__ bc,
               float* __restrict__ out)
{
    const int tid = threadIdx.x;
    const int l   = tid & 63;    // lane
    const int m   = tid & 31;    // owned state index (replicated 4x)
    const int hf  = (l >> 5);    // lane half within wave (L3 K-split)
    const int grp = tid >> 5;    // 32-lane group 0..3 (head assignment)

    __shared__ __align__(16) float z1buf[128];
    __shared__ __align__(16) float z2buf[128];

    // ---- weights into registers (thread j = column j for L1/L2) ----
    float w1r[40];
#pragma unroll
    for (int i = 0; i < 40; ++i) w1r[i] = W1[i * 128 + tid];
    const float b1r = b1[tid];

    float w2r[128];
#pragma unroll
    for (int i = 0; i < 128; ++i) w2r[i] = W2[i * 128 + tid];
    const float b2r = b2[tid];

    // L3: output m, this lane-half's K range [64*hf, 64*hf+64)
    float w3h[64];
#pragma unroll
    for (int i = 0; i < 64; ++i) w3h[i] = W3[(64 * hf + i) * 32 + m];
    const float b3r = b3[m];

    // heads: group 0 -> d, 1 -> t, 2 -> c, 3 -> dup of d (store masked off)
    float whr, bhr;
    if (grp == 1)      { whr = Wt[m]; bhr = bt[0]; }
    else if (grp == 2) { whr = Wc[m]; bhr = bc[0]; }
    else               { whr = Wd[m]; bhr = bd[0]; }
    const bool head_store = ((l & 31) == 0) && (grp < 3);
    float* const head_out = out + (grp < 3 ? grp : 0) * T_STEPS;

    const float DT  = 5.0f / 60.0f;
    const float HDT = 0.5f * DT;
    const float W6  = DT / 6.0f;

    // state replicated: lane holds h[m], x[m]; identical bits on all lanes
    float h = h0[m];
    float x = h;
    float kacc = 0.0f;
    float hist[16];

    float4 ua = *(const float4*)(U);
    float4 ub = *(const float4*)(U + 4);

    for (int t = 0; t < T_STEPS; ++t) {
        hist[t & 15] = h;   // heads use PRE-update h

        const int tn = (t + 1 < T_STEPS) ? (t + 1) : t;
        const float4 na = *(const float4*)(U + tn * 8);
        const float4 nb = *(const float4*)(U + tn * 8 + 4);

        const float us[8] = {ua.x, ua.y, ua.z, ua.w, ub.x, ub.y, ub.z, ub.w};

#pragma unroll
        for (int st = 0; st < 4; ++st) {
            // ---- L1: z1[j] = silu([x,u] @ W1 + b1); x via readlane (R0 chains) ----
            float a0 = b1r, a1 = 0.0f, a2 = 0.0f, a3 = 0.0f;
#pragma unroll
            for (int i4 = 0; i4 < 8; ++i4) {
                a0 += rl_f(x, 4 * i4)     * w1r[4 * i4];
                a1 += rl_f(x, 4 * i4 + 1) * w1r[4 * i4 + 1];
                a2 += rl_f(x, 4 * i4 + 2) * w1r[4 * i4 + 2];
                a3 += rl_f(x, 4 * i4 + 3) * w1r[4 * i4 + 3];
            }
#pragma unroll
            for (int i = 0; i < 8; ++i) a0 += us[i] * w1r[32 + i];
            const float z1 = silu_f((a0 + a1) + (a2 + a3));
            z1buf[tid] = z1;
            __syncthreads();

            // ---- L2: z2[j], K=0..127 via LDS float4 (EXACT R0 form) ----
            a0 = b2r; a1 = 0.0f; a2 = 0.0f; a3 = 0.0f;
            const float4* zb4 = (const float4*)z1buf;
#pragma unroll
            for (int i4 = 0; i4 < 32; ++i4) {
                const float4 v = zb4[i4];
                a0 += v.x * w2r[4 * i4];
                a1 += v.y * w2r[4 * i4 + 1];
                a2 += v.z * w2r[4 * i4 + 2];
                a3 += v.w * w2r[4 * i4 + 3];
            }
            const float z2 = silu_f((a0 + a1) + (a2 + a3));
            z2buf[tid] = z2;
            __syncthreads();

            // ---- L3: drift[m]; this half does its 2 segments, xor(32) exchange ----
            float pseg[2];
#pragma unroll
            for (int s2 = 0; s2 < 2; ++s2) {
                float c0 = 0.0f, c1 = 0.0f, c2 = 0.0f, c3 = 0.0f;
                const float4* z2s = (const float4*)(z2buf + 64 * hf + 32 * s2);
#pragma unroll
                for (int i4 = 0; i4 < 8; ++i4) {
                    const float4 v = z2s[i4];
                    c0 += v.x * w3h[32 * s2 + 4 * i4];
                    c1 += v.y * w3h[32 * s2 + 4 * i4 + 1];
                    c2 += v.z * w3h[32 * s2 + 4 * i4 + 2];
                    c3 += v.w * w3h[32 * s2 + 4 * i4 + 3];
                }
                pseg[s2] = (c0 + c1) + (c2 + c3);
            }
            const float sp = pseg[0] + pseg[1];          // (p0+p1) or (p2+p3)
            const float o  = __shfl_xor(sp, 32);
            // R0 order: ((p0+p1)+(p2+p3)) + b3
            const float drift = ((hf == 0) ? (sp + o) : (o + sp)) + b3r;

            // ---- RK combine, replicated; EXACT R0 expressions ----
            {
                const float k = 0.02f * drift - 0.1f * x;
                if (st == 0) {
                    kacc = k;
                    x = h + HDT * k;
                } else if (st == 1) {
                    kacc += 2.0f * k;
                    x = h + HDT * k;
                } else if (st == 2) {
                    kacc += 2.0f * k;
                    x = h + DT * k;
                } else {
                    kacc += k;
                    float hn = h + W6 * kacc;
                    if (!isfinite(hn)) hn = 0.0f;   // nan_to_num BEFORE tanh
                    hn = tanhf(hn);
                    hn = fminf(fmaxf(hn, -5.0f), 5.0f);
                    h = hn;
                    x = hn;
                }
            }
        }

        ua = na; ub = nb;

        // ---- batched heads: every 16 steps, R0's exact xor-trees ----
        if ((t & 15) == 15) {
            const int tb = t - 15;
#pragma unroll
            for (int r = 0; r < 16; ++r) {
                float p = hist[r] * whr;
#pragma unroll
                for (int s = 16; s >= 1; s >>= 1) p += __shfl_xor(p, s);
                if (head_store) head_out[tb + r] = p + bhr;
            }
        }
    }

    if (tid < 32) out[3 * T_STEPS + tid] = h;
}

extern "C" void kernel_launch(void* const* d_in, const int* in_sizes, int n_in,
                              void* d_out, int out_size, void* d_ws, size_t ws_size,
                              hipStream_t stream) {
    const float* U  = (const float*)d_in[0];
    const float* h0 = (const float*)d_in[1];
    const float* W1 = (const float*)d_in[2];
    const float* b1 = (const float*)d_in[3];
    const float* W2 = (const float*)d_in[4];
    const float* b2 = (const float*)d_in[5];
    const float* W3 = (const float*)d_in[6];
    const float* b3 = (const float*)d_in[7];
    const float* Wd = (const float*)d_in[8];
    const float* bd = (const float*)d_in[9];
    const float* Wt = (const float*)d_in[10];
    const float* bt = (const float*)d_in[11];
    const float* Wc = (const float*)d_in[12];
    const float* bc = (const float*)d_in[13];
    float* out = (float*)d_out;

    node_scan<<<1, 128, 0, stream>>>(U, h0, W1, b1, W2, b2, W3, b3,
                                     Wd, bd, Wt, bt, Wc, bc, out);
}

// Round 6
// 539241.406 us; speedup vs baseline: 1.1729x; 1.1729x over previous
//
#include <hip/hip_runtime.h>
#include <math.h>

// ControlledNODE: sequential RK4 scan, T=65536, 1 block / 128 threads (2 waves).
// R5 = R4 minus the scratch disasters:
//  - NO dynamically-indexed private arrays (R4's hist[t&15] forced scratch:
//    VGPR capped at 256, WRITE_SIZE noise 805-1324KB vs 768KB, dur +85k)
//  - heads computed per-step with the 4-group xor-tree (bit-exact, ~12 instr)
//  - u loaded as uniform scalars (compiler -> s_load, SGPR) - frees ~16 VGPRs
// Kept from R4 (bit-exactness verified twice: absmax == 6.103516e-05):
//  - L1 x-broadcast via v_readlane (no xbuf write/barrier)
//  - L2 via LDS ds_read_b128 (dense; R0's exact chain order)
//  - L3 K-split across lane halves + one shfl_xor(32), R0's segment association
//  - 2 barriers/stage = 8/step (R0 had 16)
// Numerics contract (R1/R2 lesson): every output scalar's fma-chain order must
// match R0 exactly; any re-association re-rolls the 65536-step trajectory.

constexpr int T_STEPS = 65536;

__device__ __forceinline__ float rl_f(float v, int i) {
    return __uint_as_float(__builtin_amdgcn_readlane(__float_as_uint(v), i));
}
__device__ __forceinline__ float silu_f(float a) {
    return a / (1.0f + __expf(-a));   // EXACT R0 form, IEEE divide
}

__global__ __launch_bounds__(128, 1)
void node_scan(const float* __restrict__ U,
               const float* __restrict__ h0,
               const float* __restrict__ W1, const float* __restrict__ b1,
               const float* __restrict__ W2, const float* __restrict__ b2,
               const float* __restrict__ W3, const float* __restrict__ b3,
               const float* __restrict__ Wd, const float* __restrict__ bd,
               const float* __restrict__ Wt, const float* __restrict__ bt,
               const float* __restrict__ Wc, const float* __restrict__ bc,
               float* __restrict__ out)
{
    const int tid = threadIdx.x;
    const int l   = tid & 63;    // lane
    const int m   = tid & 31;    // owned state index (replicated 4x)
    const int hf  = (l >> 5);    // lane half within wave (L3 K-split)
    const int grp = tid >> 5;    // 32-lane group 0..3 (head assignment)

    __shared__ __align__(16) float z1buf[128];
    __shared__ __align__(16) float z2buf[128];

    // ---- weights into registers (thread j = column j for L1/L2) ----
    float w1r[40];
#pragma unroll
    for (int i = 0; i < 40; ++i) w1r[i] = W1[i * 128 + tid];
    const float b1r = b1[tid];

    float w2r[128];
#pragma unroll
    for (int i = 0; i < 128; ++i) w2r[i] = W2[i * 128 + tid];
    const float b2r = b2[tid];

    // L3: output m, this lane-half's K range [64*hf, 64*hf+64)
    float w3h[64];
#pragma unroll
    for (int i = 0; i < 64; ++i) w3h[i] = W3[(64 * hf + i) * 32 + m];
    const float b3r = b3[m];

    // heads: group 0 -> d, 1 -> t, 2 -> c, 3 -> dup of d (store masked off)
    float whr, bhr;
    if (grp == 1)      { whr = Wt[m]; bhr = bt[0]; }
    else if (grp == 2) { whr = Wc[m]; bhr = bc[0]; }
    else               { whr = Wd[m]; bhr = bd[0]; }
    const bool head_store = ((l & 31) == 0) && (grp < 3);
    float* const head_out = out + (grp < 3 ? grp : 0) * T_STEPS;

    const float DT  = 5.0f / 60.0f;
    const float HDT = 0.5f * DT;
    const float W6  = DT / 6.0f;

    // state replicated: lane holds h[m], x[m]; identical bits on all lanes
    float h = h0[m];
    float x = h;
    float kacc = 0.0f;

    for (int t = 0; t < T_STEPS; ++t) {
        // ---- heads from current h (pre-update); R0's exact xor-trees ----
        {
            float p = h * whr;
#pragma unroll
            for (int s = 16; s >= 1; s >>= 1) p += __shfl_xor(p, s);
            if (head_store) head_out[t] = p + bhr;
        }

        // u_t: uniform scalar loads -> SGPRs (compiler scalarizes)
        const float u0 = U[t * 8],     u1 = U[t * 8 + 1];
        const float u2 = U[t * 8 + 2], u3 = U[t * 8 + 3];
        const float u4 = U[t * 8 + 4], u5 = U[t * 8 + 5];
        const float u6 = U[t * 8 + 6], u7 = U[t * 8 + 7];

#pragma unroll
        for (int st = 0; st < 4; ++st) {
            // ---- L1: z1[j] = silu([x,u] @ W1 + b1); x via readlane (R0 chains) ----
            float a0 = b1r, a1 = 0.0f, a2 = 0.0f, a3 = 0.0f;
#pragma unroll
            for (int i4 = 0; i4 < 8; ++i4) {
                a0 += rl_f(x, 4 * i4)     * w1r[4 * i4];
                a1 += rl_f(x, 4 * i4 + 1) * w1r[4 * i4 + 1];
                a2 += rl_f(x, 4 * i4 + 2) * w1r[4 * i4 + 2];
                a3 += rl_f(x, 4 * i4 + 3) * w1r[4 * i4 + 3];
            }
            a0 += u0 * w1r[32]; a0 += u1 * w1r[33];
            a0 += u2 * w1r[34]; a0 += u3 * w1r[35];
            a0 += u4 * w1r[36]; a0 += u5 * w1r[37];
            a0 += u6 * w1r[38]; a0 += u7 * w1r[39];
            const float z1 = silu_f((a0 + a1) + (a2 + a3));
            z1buf[tid] = z1;
            __syncthreads();

            // ---- L2: z2[j], K=0..127 via LDS float4 (EXACT R0 form) ----
            a0 = b2r; a1 = 0.0f; a2 = 0.0f; a3 = 0.0f;
            const float4* zb4 = (const float4*)z1buf;
#pragma unroll
            for (int i4 = 0; i4 < 32; ++i4) {
                const float4 v = zb4[i4];
                a0 += v.x * w2r[4 * i4];
                a1 += v.y * w2r[4 * i4 + 1];
                a2 += v.z * w2r[4 * i4 + 2];
                a3 += v.w * w2r[4 * i4 + 3];
            }
            const float z2 = silu_f((a0 + a1) + (a2 + a3));
            z2buf[tid] = z2;
            __syncthreads();

            // ---- L3: drift[m]; this half does its 2 segments, xor(32) exchange ----
            float pseg[2];
#pragma unroll
            for (int s2 = 0; s2 < 2; ++s2) {
                float c0 = 0.0f, c1 = 0.0f, c2 = 0.0f, c3 = 0.0f;
                const float4* z2s = (const float4*)(z2buf + 64 * hf + 32 * s2);
#pragma unroll
                for (int i4 = 0; i4 < 8; ++i4) {
                    const float4 v = z2s[i4];
                    c0 += v.x * w3h[32 * s2 + 4 * i4];
                    c1 += v.y * w3h[32 * s2 + 4 * i4 + 1];
                    c2 += v.z * w3h[32 * s2 + 4 * i4 + 2];
                    c3 += v.w * w3h[32 * s2 + 4 * i4 + 3];
                }
                pseg[s2] = (c0 + c1) + (c2 + c3);
            }
            const float sp = pseg[0] + pseg[1];          // (p0+p1) or (p2+p3)
            const float o  = __shfl_xor(sp, 32);
            // R0 order: ((p0+p1)+(p2+p3)) + b3
            const float drift = ((hf == 0) ? (sp + o) : (o + sp)) + b3r;

            // ---- RK combine, replicated; EXACT R0 expressions ----
            {
                const float k = 0.02f * drift - 0.1f * x;
                if (st == 0) {
                    kacc = k;
                    x = h + HDT * k;
                } else if (st == 1) {
                    kacc += 2.0f * k;
                    x = h + HDT * k;
                } else if (st == 2) {
                    kacc += 2.0f * k;
                    x = h + DT * k;
                } else {
                    kacc += k;
                    float hn = h + W6 * kacc;
                    if (!isfinite(hn)) hn = 0.0f;   // nan_to_num BEFORE tanh
                    hn = tanhf(hn);
                    hn = fminf(fmaxf(hn, -5.0f), 5.0f);
                    h = hn;
                    x = hn;
                }
            }
        }
    }

    if (tid < 32) out[3 * T_STEPS + tid] = h;
}

extern "C" void kernel_launch(void* const* d_in, const int* in_sizes, int n_in,
                              void* d_out, int out_size, void* d_ws, size_t ws_size,
                              hipStream_t stream) {
    const float* U  = (const float*)d_in[0];
    const float* h0 = (const float*)d_in[1];
    const float* W1 = (const float*)d_in[2];
    const float* b1 = (const float*)d_in[3];
    const float* W2 = (const float*)d_in[4];
    const float* b2 = (const float*)d_in[5];
    const float* W3 = (const float*)d_in[6];
    const float* b3 = (const float*)d_in[7];
    const float* Wd = (const float*)d_in[8];
    const float* bd = (const float*)d_in[9];
    const float* Wt = (const float*)d_in[10];
    const float* bt = (const float*)d_in[11];
    const float* Wc = (const float*)d_in[12];
    const float* bc = (const float*)d_in[13];
    float* out = (float*)d_out;

    node_scan<<<1, 128, 0, stream>>>(U, h0, W1, b1, W2, b2, W3, b3,
                                     Wd, bd, Wt, bt, Wc, bc, out);
}